// Round 1
// baseline (193.168 us; speedup 1.0000x reference)
//
#include <hip/hip_runtime.h>
#include <stdint.h>

typedef unsigned short u16;
typedef unsigned int u32;
typedef __attribute__((ext_vector_type(8))) short bf16x8;   // 8 bf16 = 4 VGPR (MFMA A/B frag)
typedef __attribute__((ext_vector_type(4))) float f32x4;    // MFMA C/D frag
typedef __attribute__((ext_vector_type(4))) unsigned short u16x4;

#define DEVI static __device__ __forceinline__

DEVI u16 f2bf(float f){ union{float f; unsigned u;} x; x.f=f;
  unsigned r = x.u + 0x7FFFu + ((x.u>>16)&1u); return (u16)(r>>16); }
// round-half-up bf16 (2 VALU ops): max bias 0.5 ulp, fine at this tolerance
DEVI u16 f2bf_fast(float f){ union{float f; unsigned u;} x; x.f=f;
  return (u16)((x.u + 0x8000u)>>16); }

// async global->LDS, 16B per lane. LDS dest must be wave-uniform base (HW adds lane*16).
DEVI void gload16(const void* g, void* l){
  __builtin_amdgcn_global_load_lds((const __attribute__((address_space(1))) u32*)g,
                                   (__attribute__((address_space(3))) u32*)l, 16, 0, 0);
}

// ---------------- prep: hidden f32->bf16 + both weight transposes, one dispatch ----
__global__ void __launch_bounds__(256) prep_k(const float* __restrict__ hidden,
      const float* __restrict__ wqkv, const float* __restrict__ wproj,
      u16* __restrict__ Acv, u16* __restrict__ WqkvT, u16* __restrict__ WprojT){
  __shared__ u16 t[32][33];
  int bid = blockIdx.x, tid = threadIdx.x;
  if (bid < 3072){                       // cvt hidden: 8 floats/thread
    int i = bid*2048 + tid*8;
    float4 a = *(const float4*)(hidden+i), b = *(const float4*)(hidden+i+4);
    u16x4 lo = { f2bf(a.x), f2bf(a.y), f2bf(a.z), f2bf(a.w) };
    u16x4 hi = { f2bf(b.x), f2bf(b.y), f2bf(b.z), f2bf(b.w) };
    *(u16x4*)(Acv+i) = lo; *(u16x4*)(Acv+i+4) = hi;
    return;
  }
  const float* in; u16* outp; int C, bx, by;
  if (bid < 4800){ int tt = bid-3072; bx = tt%72; by = tt/72; in = wqkv;  outp = WqkvT;  C = 2304; }
  else           { int tt = bid-4800; bx = tt%24; by = tt/24; in = wproj; outp = WprojT; C = 768;  }
  int tx = tid&31, ty = tid>>5;          // 32 x 8
  int c0 = bx*32, r0 = by*32;
  for (int i=0;i<4;i++)
    t[ty+i*8][tx] = f2bf(in[(size_t)(r0+ty+i*8)*C + c0+tx]);
  __syncthreads();
  for (int i=0;i<4;i++) outp[(size_t)(c0+ty+i*8)*768 + r0+tx] = t[tx][ty+i*8];
}

// ------- merged QKV GEMM v2: ring-3 LDS pipeline + global_load_lds + counted vmcnt --
// BM=256 BN=128 BK=64. 512 thr = 8 waves (4M x 2N), 64x64 out per wave.
// LDS = 3 tile-slots (A 32KB + B 16KB each = 144KB, 1 block/CU). Tile t computes
// from slot t%3 while slot (t+2)%3 is staged by 6 global_load_lds_dwordx4/thread
// (pre-swizzled global source, linear LDS dest; XOR row&7 granule swizzle =
// conflict-free, same layout as the proven relay kernel).
// One barrier + one s_waitcnt vmcnt(6) per K-tile; never drains in steady state
// (tile t+1's 6 loads stay in flight). 2-tile prefetch lead (~2x compute slack).
// Grid 576 = 8 xcd x 4 mg x 18 n: per-XCD A panel (1024x768 bf16 = 1.5MB) L2-res.
//  n0 < 1536 (Q/K): SWAPPED MFMA operands -> u16x4 into [bh][s][d]
//  n0 >= 1536 (V): normal order -> u16x4 into Vt[bh][d][s]
__global__ void __launch_bounds__(512,2) qkv_gemm(const u16* __restrict__ A,
      const u16* __restrict__ BT, const float* __restrict__ bias,
      u16* __restrict__ Qw, u16* __restrict__ Kw, u16* __restrict__ Vtw){
  __shared__ u16 As[3*16384];   // 3 x [256 m][64 k], 128B rows, granule g holds global g^(row&7)
  __shared__ u16 Bs[3*8192];    // 3 x [128 n][64 k]
  int tid = threadIdx.x, lane = tid&63, wave = tid>>6;
  int l15 = lane&15, quad = lane>>4;
  int bid = blockIdx.x;                  // 576 = 8 xcd x 8*... (4 mg x 18 n)
  int xcd = bid & 7, slot = bid >> 3;
  int mg = slot/18, nIdx = slot - mg*18;
  int m0 = (xcd*4 + mg)*256, n0 = nIdx*128;
  int wm = (wave>>1)*64, wn = (wave&1)*64;
  bool sw = (n0 < 1536);
  f32x4 acc[4][4] = {};
  const char* Ab = (const char*)A; const char* Bb = (const char*)BT;
  char* AsB = (char*)As; char* BsB = (char*)Bs;
  int rsub = lane>>3, g = lane&7;        // row-in-8 / granule of this lane's 16B
  const char* Asrc[4]; const char* Bsrc[2];
  #pragma unroll
  for (int h=0;h<4;h++){ int rl = h*64 + wave*8 + rsub;
    Asrc[h] = Ab + (size_t)(m0+rl)*1536 + ((g ^ (rl&7))<<4); }
  #pragma unroll
  for (int h=0;h<2;h++){ int rl = h*64 + wave*8 + rsub;
    Bsrc[h] = Bb + (size_t)(n0+rl)*1536 + ((g ^ (rl&7))<<4); }

  // prologue: stage tiles 0 and 1 into slots 0,1 (12 loads in flight, issue order!)
  #pragma unroll
  for (int t=0;t<2;t++){
    char* ad = AsB + t*32768 + wave*1024;
    char* bd = BsB + t*16384 + wave*1024;
    #pragma unroll
    for (int h=0;h<4;h++) gload16(Asrc[h] + t*128, ad + h*8192);
    #pragma unroll
    for (int h=0;h<2;h++) gload16(Bsrc[h] + t*128, bd + h*8192);
  }

  for (int tb=0; tb<12; tb+=3){
    #pragma unroll
    for (int ti=0; ti<3; ++ti){
      int t = tb + ti;
      // ---- tile boundary: wait tile t staged (keep t+1's 6 loads in flight) ----
      __builtin_amdgcn_sched_barrier(0);
      if (t < 11) asm volatile("s_waitcnt vmcnt(6)" ::: "memory");
      else        asm volatile("s_waitcnt vmcnt(0)" ::: "memory");
      __builtin_amdgcn_sched_barrier(0);
      __builtin_amdgcn_s_barrier();
      __builtin_amdgcn_sched_barrier(0);
      asm volatile("" ::: "memory");
      // ---- issue staging of tile t+2 into slot (ti+2)%3 (free since barrier) ----
      if (t < 10){
        int c2 = (ti>=1) ? ti-1 : 2;     // (ti+2)%3
        char* ad = AsB + c2*32768 + wave*1024;
        char* bd = BsB + c2*16384 + wave*1024;
        size_t ko = (size_t)(t+2)*128;
        #pragma unroll
        for (int h=0;h<4;h++) gload16(Asrc[h] + ko, ad + h*8192);
        #pragma unroll
        for (int h=0;h<2;h++) gload16(Bsrc[h] + ko, bd + h*8192);
      }
      __builtin_amdgcn_sched_barrier(0);
      // ---- compute tile t from slot ti: 2 k-phases x 16 MFMA ----
      const char* Abase = AsB + ti*32768;
      const char* Bbase = BsB + ti*16384;
      #pragma unroll
      for (int kh=0;kh<2;kh++){
        bf16x8 af[4], bfr[4];
        #pragma unroll
        for (int i=0;i<4;i++){
          int ma = wm + i*16 + l15;
          af[i] = *(const bf16x8*)(Abase + ma*128 + (((kh*4+quad) ^ (ma&7))<<4));
        }
        #pragma unroll
        for (int j=0;j<4;j++){
          int nb = wn + j*16 + l15;
          bfr[j] = *(const bf16x8*)(Bbase + nb*128 + (((kh*4+quad) ^ (nb&7))<<4));
        }
        __builtin_amdgcn_s_setprio(1);
        if (sw){
          #pragma unroll
          for (int p=0;p<4;p++)
            #pragma unroll
            for (int q=0;q<4;q++)
              acc[p][q] = __builtin_amdgcn_mfma_f32_16x16x32_bf16(bfr[p], af[q], acc[p][q], 0,0,0);
        } else {
          #pragma unroll
          for (int p=0;p<4;p++)
            #pragma unroll
            for (int q=0;q<4;q++)
              acc[p][q] = __builtin_amdgcn_mfma_f32_16x16x32_bf16(af[p], bfr[q], acc[p][q], 0,0,0);
        }
        __builtin_amdgcn_s_setprio(0);
      }
    }
  }

  if (sw){
    int c3 = (n0 >= 768);
    u16* dst = c3 ? Kw : Qw;
    float scl = c3 ? 1.0f : 0.180336884f;   // Q: 0.125 * log2(e) folded for exp2 path
    int nb = n0 - c3*768;
    #pragma unroll
    for (int p=0;p<4;p++){
      float4 bv4 = *(const float4*)(bias + n0 + wn + p*16 + quad*4);
      int rem = nb + wn + p*16 + quad*4;
      int hh = rem>>6, d0 = rem&63;
      #pragma unroll
      for (int q=0;q<4;q++){
        int mrow = m0 + wm + q*16 + l15;
        int b = mrow>>10, sl = mrow&1023;
        u16x4 pk;
        pk[0]=f2bf((acc[p][q][0]+bv4.x)*scl); pk[1]=f2bf((acc[p][q][1]+bv4.y)*scl);
        pk[2]=f2bf((acc[p][q][2]+bv4.z)*scl); pk[3]=f2bf((acc[p][q][3]+bv4.w)*scl);
        *(u16x4*)(dst + ((size_t)(b*12+hh)*1024 + sl)*64 + d0) = pk;
      }
    }
  } else {
    #pragma unroll
    for (int q=0;q<4;q++){
      float bv = bias[n0+wn+q*16+l15];
      int rem = (n0-1536) + wn + q*16 + l15;
      int hh = rem>>6, d = rem&63;
      #pragma unroll
      for (int p=0;p<4;p++){
        int mrow = m0 + wm + p*16 + quad*4;
        int b = mrow>>10, sl = mrow&1023;
        u16x4 pk;
        for (int r=0;r<4;r++) pk[r] = f2bf(acc[p][q][r] + bv);
        *(u16x4*)(Vtw + ((size_t)(b*12+hh)*64 + d)*1024 + sl) = pk;
      }
    }
  }
}

// ------ flash attention (round-11 proven + raw v_exp_f32) --------------------------
// grid (96 bh, 8 q-tiles), block 256 = 4 waves; each wave owns 32 queries.
// 32KB LDS (grid gives 3 blocks/CU). Chunk c+1 prefetched global->VGPR during
// compute of c; after the read barrier the relay is ds_written into the same
// buffers. Neither barrier drains global vmcnt. No-max softmax (scores pre-scaled
// by 0.125*log2e): P = exp2(S) via __builtin_amdgcn_exp2f (bare v_exp_f32, no libm
// range fixup -- inputs bounded). Denominators via ones-row MFMA. 96 % 8 == 0 ->
// all q-blocks of a bh share an XCD, K/V reads L2-local.
__global__ void __launch_bounds__(256) attn_k(const u16* __restrict__ Qw,
      const u16* __restrict__ Kw, const u16* __restrict__ Vtw, u16* __restrict__ ctx){
  __shared__ u16 Ks[4096];     // [64 key][64 d]  128B rows, granule ^= key&7
  __shared__ u16 Vts[4096];    // [64 d][64 key]  128B rows, granule ^= d&7
  __shared__ u16 Ps[4][2048];  // per-wave P/O: [32 q][64] 128B rows, granule ^= q&7
  int tid = threadIdx.x, wave = tid>>6, lane = tid&63;
  int l15 = lane&15, quad = lane>>4;
  int bh = blockIdx.x;
  int q0w = blockIdx.y*128 + wave*32;
  const u16* Qb  = Qw + (size_t)bh*65536;
  const char* KbB = (const char*)(Kw + (size_t)bh*65536);
  const char* VbB = (const char*)(Vtw + (size_t)bh*65536);
  char* KsB = (char*)Ks; char* VtsB = (char*)Vts;
  char* PwB = (char*)(&Ps[wave][0]);

  bf16x8 qa[2][2];
  for (int qt=0;qt<2;qt++) for (int c=0;c<2;c++)
    qa[qt][c] = *(const bf16x8*)(Qb + (size_t)(q0w+qt*16+l15)*64 + c*32 + quad*8);

  bf16x8 ones_f;
  for (int t=0;t<8;t++) ones_f[t] = (short)0x3F80;   // bf16 1.0

  f32x4 oacc[4][2] = {};   // [dt][qt]: O^T row d=dt*16+quad*4+r, col q=qt*16+l15
  f32x4 lacc[2] = {};      // denominator (all r equal)

  int rr = tid>>3, gs = tid&7;          // staging: row-in-half / stored granule
  int gsw = (gs ^ (rr&7)) << 4;         // swizzled source granule byte offset
  int ldst = tid*16;
  const char* Kg0 = KbB + (size_t)rr*128      + gsw;   // + c*64*128 per chunk
  const char* Kg1 = KbB + (size_t)(rr+32)*128 + gsw;
  const char* Vg0 = VbB + (size_t)rr*2048      + gsw;  // + c*64*2 per chunk
  const char* Vg1 = VbB + (size_t)(rr+32)*2048 + gsw;

  // stage chunk 0 via relay
  bf16x8 krel0 = *(const bf16x8*)Kg0, krel1 = *(const bf16x8*)Kg1;
  bf16x8 vrel0 = *(const bf16x8*)Vg0, vrel1 = *(const bf16x8*)Vg1;
  *(bf16x8*)(KsB + ldst)  = krel0;  *(bf16x8*)(KsB + 4096 + ldst)  = krel1;
  *(bf16x8*)(VtsB + ldst) = vrel0;  *(bf16x8*)(VtsB + 4096 + ldst) = vrel1;
  __syncthreads();

  for (int c=0; c<16; c++){
    if (c < 15){                          // prefetch chunk c+1 into relay regs
      size_t kk = (size_t)(c+1)*64;
      krel0 = *(const bf16x8*)(Kg0 + kk*128);
      krel1 = *(const bf16x8*)(Kg1 + kk*128);
      vrel0 = *(const bf16x8*)(Vg0 + kk*2);
      vrel1 = *(const bf16x8*)(Vg1 + kk*2);
    }
    // ---- QK: S^T[64k x 32q], K-dim 64 in two 32-chunks ----
    f32x4 st[4][2];
    for (int kt=0;kt<4;kt++){
      int key = kt*16 + l15;
      const char* krow = KsB + key*128;
      bf16x8 ka0 = *(const bf16x8*)(krow + (((quad  ) ^ (key&7))<<4));
      bf16x8 ka1 = *(const bf16x8*)(krow + (((quad+4) ^ (key&7))<<4));
      for (int qt=0;qt<2;qt++){
        f32x4 s = {};
        s = __builtin_amdgcn_mfma_f32_16x16x32_bf16(ka0, qa[qt][0], s, 0,0,0);
        s = __builtin_amdgcn_mfma_f32_16x16x32_bf16(ka1, qa[qt][1], s, 0,0,0);
        st[kt][qt] = s;
      }
    }
    // ---- P = exp2(st) (raw v_exp_f32), pack to bf16, stage to LDS ----
    for (int qt=0;qt<2;qt++){
      int q = qt*16 + l15;
      for (int kt=0;kt<4;kt++){
        u16x4 pk;
        for (int r=0;r<4;r++) pk[r] = f2bf_fast(__builtin_amdgcn_exp2f(st[kt][qt][r]));
        int g = kt*2 + (quad>>1);
        *(u16x4*)(PwB + q*128 + ((g ^ (l15&7))<<4) + (quad&1)*8) = pk;
      }
    }
    // ---- PV: O^T += V^T * P^T ; l += ones * P^T ----
    bf16x8 bp[2][2];
    for (int qt=0;qt<2;qt++){
      int q = qt*16 + l15;
      bp[qt][0] = *(const bf16x8*)(PwB + q*128 + (((quad  ) ^ (l15&7))<<4));
      bp[qt][1] = *(const bf16x8*)(PwB + q*128 + (((quad+4) ^ (l15&7))<<4));
      lacc[qt] = __builtin_amdgcn_mfma_f32_16x16x32_bf16(ones_f, bp[qt][0], lacc[qt], 0,0,0);
      lacc[qt] = __builtin_amdgcn_mfma_f32_16x16x32_bf16(ones_f, bp[qt][1], lacc[qt], 0,0,0);
    }
    for (int dt=0;dt<4;dt++){
      int d = dt*16 + l15;
      const char* vrow = VtsB + d*128;
      bf16x8 av0 = *(const bf16x8*)(vrow + (((quad  ) ^ (d&7))<<4));
      bf16x8 av1 = *(const bf16x8*)(vrow + (((quad+4) ^ (d&7))<<4));
      for (int qt=0;qt<2;qt++){
        oacc[dt][qt] = __builtin_amdgcn_mfma_f32_16x16x32_bf16(av0, bp[qt][0], oacc[dt][qt], 0,0,0);
        oacc[dt][qt] = __builtin_amdgcn_mfma_f32_16x16x32_bf16(av1, bp[qt][1], oacc[dt][qt], 0,0,0);
      }
    }
    __syncthreads();                      // all waves done reading Ks/Vts (lgkm only)
    if (c < 15){
      *(bf16x8*)(KsB + ldst)  = krel0;  *(bf16x8*)(KsB + 4096 + ldst)  = krel1;
      *(bf16x8*)(VtsB + ldst) = vrel0;  *(bf16x8*)(VtsB + 4096 + ldst) = vrel1;
      __syncthreads();                    // staging visible (lgkm only)
    }
  }

  // ---- epilogue: normalize, transpose O^T->O via per-wave Ps, coalesced store ----
  float rinv[2] = { 1.0f/lacc[0][0], 1.0f/lacc[1][0] };
  int b = bh/12, hh = bh - b*12;
  for (int qt=0;qt<2;qt++){
    int q = qt*16 + l15;
    for (int dt=0;dt<4;dt++){
      u16x4 pk;
      for (int r=0;r<4;r++) pk[r] = f2bf_fast(oacc[dt][qt][r]*rinv[qt]);
      int g = dt*2 + (quad>>1);
      *(u16x4*)(PwB + q*128 + ((g ^ (l15&7))<<4) + (quad&1)*8) = pk;
    }
  }
  char* ctxB = (char*)ctx;
  for (int ro=0; ro<4; ro++){            // 32 rows x 8 granules = 4 rounds of 64 lanes
    int q = ro*8 + (lane>>3);
    int gg = lane&7;
    bf16x8 v = *(const bf16x8*)(PwB + q*128 + ((gg ^ (q&7))<<4));
    size_t tok = (size_t)b*1024 + blockIdx.y*128 + wave*32 + q;
    *(bf16x8*)(ctxB + (tok*768 + hh*64 + gg*8)*2) = v;
  }
}

// -------- proj GEMM v2: same ring-3 counted-vmcnt template, out f32 ---------------
// BM=256 BN=128 BK=64, 512 thr / 8 waves, grid 192 = 8 xcd x 4 mg x 6 n (single
// generation: all blocks resident at once, no tail).
__global__ void __launch_bounds__(512,2) proj_gemm(const u16* __restrict__ A,
      const u16* __restrict__ BT, const float* __restrict__ bias,
      float* __restrict__ of){
  __shared__ u16 As[3*16384];   // 3 x [256 m][64 k]
  __shared__ u16 Bs[3*8192];    // 3 x [128 n][64 k]
  int tid = threadIdx.x, lane = tid&63, wave = tid>>6;
  int l15 = lane&15, quad = lane>>4;
  int bid = blockIdx.x;
  int xcd = bid & 7, slot = bid >> 3;
  int mg = slot/6, nIdx = slot - mg*6;
  int m0 = (xcd*4 + mg)*256, n0 = nIdx*128;
  int wm = (wave>>1)*64, wn = (wave&1)*64;
  f32x4 acc[4][4] = {};
  const char* Ab = (const char*)A; const char* Bb = (const char*)BT;
  char* AsB = (char*)As; char* BsB = (char*)Bs;
  int rsub = lane>>3, g = lane&7;
  const char* Asrc[4]; const char* Bsrc[2];
  #pragma unroll
  for (int h=0;h<4;h++){ int rl = h*64 + wave*8 + rsub;
    Asrc[h] = Ab + (size_t)(m0+rl)*1536 + ((g ^ (rl&7))<<4); }
  #pragma unroll
  for (int h=0;h<2;h++){ int rl = h*64 + wave*8 + rsub;
    Bsrc[h] = Bb + (size_t)(n0+rl)*1536 + ((g ^ (rl&7))<<4); }

  #pragma unroll
  for (int t=0;t<2;t++){
    char* ad = AsB + t*32768 + wave*1024;
    char* bd = BsB + t*16384 + wave*1024;
    #pragma unroll
    for (int h=0;h<4;h++) gload16(Asrc[h] + t*128, ad + h*8192);
    #pragma unroll
    for (int h=0;h<2;h++) gload16(Bsrc[h] + t*128, bd + h*8192);
  }

  for (int tb=0; tb<12; tb+=3){
    #pragma unroll
    for (int ti=0; ti<3; ++ti){
      int t = tb + ti;
      __builtin_amdgcn_sched_barrier(0);
      if (t < 11) asm volatile("s_waitcnt vmcnt(6)" ::: "memory");
      else        asm volatile("s_waitcnt vmcnt(0)" ::: "memory");
      __builtin_amdgcn_sched_barrier(0);
      __builtin_amdgcn_s_barrier();
      __builtin_amdgcn_sched_barrier(0);
      asm volatile("" ::: "memory");
      if (t < 10){
        int c2 = (ti>=1) ? ti-1 : 2;     // (ti+2)%3
        char* ad = AsB + c2*32768 + wave*1024;
        char* bd = BsB + c2*16384 + wave*1024;
        size_t ko = (size_t)(t+2)*128;
        #pragma unroll
        for (int h=0;h<4;h++) gload16(Asrc[h] + ko, ad + h*8192);
        #pragma unroll
        for (int h=0;h<2;h++) gload16(Bsrc[h] + ko, bd + h*8192);
      }
      __builtin_amdgcn_sched_barrier(0);
      const char* Abase = AsB + ti*32768;
      const char* Bbase = BsB + ti*16384;
      #pragma unroll
      for (int kh=0;kh<2;kh++){
        bf16x8 af[4], bfr[4];
        #pragma unroll
        for (int i=0;i<4;i++){
          int ma = wm + i*16 + l15;
          af[i] = *(const bf16x8*)(Abase + ma*128 + (((kh*4+quad) ^ (ma&7))<<4));
        }
        #pragma unroll
        for (int j=0;j<4;j++){
          int nb = wn + j*16 + l15;
          bfr[j] = *(const bf16x8*)(Bbase + nb*128 + (((kh*4+quad) ^ (nb&7))<<4));
        }
        __builtin_amdgcn_s_setprio(1);
        #pragma unroll
        for (int p=0;p<4;p++)
          #pragma unroll
          for (int q=0;q<4;q++)
            acc[p][q] = __builtin_amdgcn_mfma_f32_16x16x32_bf16(af[p], bfr[q], acc[p][q], 0,0,0);
        __builtin_amdgcn_s_setprio(0);
      }
    }
  }

  float bv[4];
  #pragma unroll
  for (int j=0;j<4;j++) bv[j] = bias[n0+wn+j*16+l15];
  #pragma unroll
  for (int p=0;p<4;p++){
    int mb = m0 + wm + p*16 + quad*4;
    #pragma unroll
    for (int j=0;j<4;j++){
      int ncol = wn + j*16 + l15;
      for (int r=0;r<4;r++)
        of[(size_t)(mb+r)*768 + n0 + ncol] = acc[p][j][r] + bv[j];
    }
  }
}

extern "C" void kernel_launch(void* const* d_in, const int* in_sizes, int n_in,
                              void* d_out, int out_size, void* d_ws, size_t ws_size,
                              hipStream_t stream){
  const float* hidden = (const float*)d_in[0];
  const float* wqkv   = (const float*)d_in[1];
  const float* bqkv   = (const float*)d_in[2];
  const float* wproj  = (const float*)d_in[3];
  const float* bproj  = (const float*)d_in[4];
  float* out = (float*)d_out;
  char* ws = (char*)d_ws;
  u16* Acv    = (u16*)(ws);                                   // [8192][768] bf16
  u16* WqkvT  = (u16*)(ws + 12582912);                        // 2304x768
  u16* WprojT = (u16*)(ws + 12582912 + 3538944);              // 768x768
  char* base2 = ws + 12582912 + 3538944 + 1179648;
  u16* Qw     = (u16*)(base2);                                // [96][1024][64] (pre-scaled)
  u16* Kw     = (u16*)(base2 + 12582912);                     // [96][1024][64]
  u16* Vtw    = (u16*)(base2 + (size_t)2*12582912);           // [96][64][1024]
  u16* ctx    = (u16*)(base2 + (size_t)3*12582912);           // [8192][768] bf16

  prep_k<<<5376, 256, 0, stream>>>(hidden, wqkv, wproj, Acv, WqkvT, WprojT);
  qkv_gemm<<<576, 512, 0, stream>>>(Acv, WqkvT, bqkv, Qw, Kw, Vtw);
  attn_k<<<dim3(96,8), 256, 0, stream>>>(Qw, Kw, Vtw, ctx);
  proj_gemm<<<192, 512, 0, stream>>>(ctx, WprojT, bproj, out);
}

// Round 2
// 175.803 us; speedup vs baseline: 1.0988x; 1.0988x over previous
//
#include <hip/hip_runtime.h>
#include <stdint.h>

typedef unsigned short u16;
typedef unsigned int u32;
typedef __attribute__((ext_vector_type(8))) short bf16x8;   // 8 bf16 = 4 VGPR (MFMA A/B frag)
typedef __attribute__((ext_vector_type(4))) float f32x4;    // MFMA C/D frag
typedef __attribute__((ext_vector_type(4))) unsigned short u16x4;

#define DEVI static __device__ __forceinline__

DEVI u16 f2bf(float f){ union{float f; unsigned u;} x; x.f=f;
  unsigned r = x.u + 0x7FFFu + ((x.u>>16)&1u); return (u16)(r>>16); }
// round-half-up bf16 (2 VALU ops): max bias 0.5 ulp, fine at this tolerance
DEVI u16 f2bf_fast(float f){ union{float f; unsigned u;} x; x.f=f;
  return (u16)((x.u + 0x8000u)>>16); }

// async global->LDS, 16B per lane. LDS dest is wave-uniform base (HW adds lane*16).
DEVI void gload16(const void* g, void* l){
  __builtin_amdgcn_global_load_lds((const __attribute__((address_space(1))) u32*)g,
                                   (__attribute__((address_space(3))) u32*)l, 16, 0, 0);
}

// ---------------- prep: hidden f32->bf16 + both weight transposes, one dispatch ----
__global__ void __launch_bounds__(256) prep_k(const float* __restrict__ hidden,
      const float* __restrict__ wqkv, const float* __restrict__ wproj,
      u16* __restrict__ Acv, u16* __restrict__ WqkvT, u16* __restrict__ WprojT){
  __shared__ u16 t[32][33];
  int bid = blockIdx.x, tid = threadIdx.x;
  if (bid < 3072){                       // cvt hidden: 8 floats/thread
    int i = bid*2048 + tid*8;
    float4 a = *(const float4*)(hidden+i), b = *(const float4*)(hidden+i+4);
    u16x4 lo = { f2bf(a.x), f2bf(a.y), f2bf(a.z), f2bf(a.w) };
    u16x4 hi = { f2bf(b.x), f2bf(b.y), f2bf(b.z), f2bf(b.w) };
    *(u16x4*)(Acv+i) = lo; *(u16x4*)(Acv+i+4) = hi;
    return;
  }
  const float* in; u16* outp; int C, bx, by;
  if (bid < 4800){ int tt = bid-3072; bx = tt%72; by = tt/72; in = wqkv;  outp = WqkvT;  C = 2304; }
  else           { int tt = bid-4800; bx = tt%24; by = tt/24; in = wproj; outp = WprojT; C = 768;  }
  int tx = tid&31, ty = tid>>5;          // 32 x 8
  int c0 = bx*32, r0 = by*32;
  for (int i=0;i<4;i++)
    t[ty+i*8][tx] = f2bf(in[(size_t)(r0+ty+i*8)*C + c0+tx]);
  __syncthreads();
  for (int i=0;i<4;i++) outp[(size_t)(c0+ty+i*8)*768 + r0+tx] = t[tx][ty+i*8];
}

// ------- merged QKV GEMM v3: round-0 geometry + ring-2 global_load_lds pipeline ----
// BM=BN=128, BK=64, 256 thr = 4 waves (2x2), 64x64 out per wave. Grid 1152 =
// 8 xcd x (mg = slot&7, n = slot>>3): n-major order (all 8 mg of one B-column
// adjacent) -> B panel read once per XCD pass; A panel (1.5MB/XCD) L2-resident.
// Staging: 8 global_load_lds_dwordx4 per thread per tile into a 2-slot LDS ring
// (2x32KB = 64KB -> 2 blocks/CU). Pre-swizzled global source + linear LDS dest
// reproduces the proven XOR row&7 granule layout. Per tile: barrier (reads of the
// overwrite target done) -> issue stage t+2 -> s_waitcnt vmcnt(8) (t+1's loads,
// issued a full compute phase ago) -> barrier. No relay VGPRs, no ds_writes, no
// vmcnt(0) drain in steady state.
//  n0 < 1536 (Q/K): SWAPPED MFMA operands -> u16x4 into [bh][s][d]
//  n0 >= 1536 (V): normal order -> u16x4 into Vt[bh][d][s]
__global__ void __launch_bounds__(256) qkv_gemm(const u16* __restrict__ A,
      const u16* __restrict__ BT, const float* __restrict__ bias,
      u16* __restrict__ Qw, u16* __restrict__ Kw, u16* __restrict__ Vtw){
  __shared__ u16 As[2*8192];   // 2 slots x [128 m][64 k], 128B rows, granule g = global g^(row&7)
  __shared__ u16 Bs[2*8192];   // 2 slots x [128 n][64 k]
  int tid = threadIdx.x, lane = tid&63, wave = tid>>6;
  int l15 = lane&15, quad = lane>>4;
  int bid = blockIdx.x;                  // 1152 = 8 xcd x 8 mg x 18 n
  int xcd = bid & 7, slot = bid >> 3;
  int mg = slot & 7, nIdx = slot >> 3;
  int m0 = (xcd*8 + mg)*128, n0 = nIdx*128;
  int wm = (wave>>1)*64, wn = (wave&1)*64;
  bool sw = (n0 < 1536);
  f32x4 acc[4][4] = {};
  const char* Ab = (const char*)A; const char* Bb = (const char*)BT;
  char* AsB = (char*)As; char* BsB = (char*)Bs;
  int rsub = lane>>3, g = lane&7;        // row-in-8 / granule of this lane's 16B
  const char* Asrc[4]; const char* Bsrc[4];
  #pragma unroll
  for (int h=0;h<4;h++){
    int rl = h*32 + wave*8 + rsub;       // == tid>>3 + 32h: identical rows to round-0
    Asrc[h] = Ab + (size_t)(m0+rl)*1536 + ((g ^ (rl&7))<<4);
    Bsrc[h] = Bb + (size_t)(n0+rl)*1536 + ((g ^ (rl&7))<<4);
  }

  auto stage = [&](int t, int s){
    char* ad = AsB + s*16384 + wave*1024;
    char* bd = BsB + s*16384 + wave*1024;
    size_t ko = (size_t)t*128;
    #pragma unroll
    for (int h=0;h<4;h++) gload16(Asrc[h] + ko, ad + h*4096);
    #pragma unroll
    for (int h=0;h<4;h++) gload16(Bsrc[h] + ko, bd + h*4096);
  };
  auto compute = [&](const char* Abase, const char* Bbase){
    #pragma unroll
    for (int c=0;c<2;c++){
      bf16x8 af[4], bfr[4];
      #pragma unroll
      for (int i=0;i<4;i++){
        int ma = wm + i*16 + l15, nb2 = wn + i*16 + l15;
        af[i]  = *(const bf16x8*)(Abase + ma*128  + (((c*4+quad) ^ (ma&7))<<4));
        bfr[i] = *(const bf16x8*)(Bbase + nb2*128 + (((c*4+quad) ^ (nb2&7))<<4));
      }
      __builtin_amdgcn_s_setprio(1);
      if (sw){
        #pragma unroll
        for (int p=0;p<4;p++)
          #pragma unroll
          for (int q=0;q<4;q++)
            acc[p][q] = __builtin_amdgcn_mfma_f32_16x16x32_bf16(bfr[p], af[q], acc[p][q], 0,0,0);
      } else {
        #pragma unroll
        for (int p=0;p<4;p++)
          #pragma unroll
          for (int q=0;q<4;q++)
            acc[p][q] = __builtin_amdgcn_mfma_f32_16x16x32_bf16(af[p], bfr[q], acc[p][q], 0,0,0);
      }
      __builtin_amdgcn_s_setprio(0);
    }
  };

  // prologue: slot0 <- tile0, slot1 <- tile1; drain tile0's 8 (oldest), keep tile1 in flight
  stage(0, 0);
  stage(1, 1);
  asm volatile("s_waitcnt vmcnt(8)" ::: "memory");
  __builtin_amdgcn_sched_barrier(0);
  __builtin_amdgcn_s_barrier();
  __builtin_amdgcn_sched_barrier(0);

  #pragma unroll 2
  for (int t=0; t<11; t++){
    compute(AsB + (t&1)*16384, BsB + (t&1)*16384);
    __builtin_amdgcn_sched_barrier(0);
    __builtin_amdgcn_s_barrier();            // all waves done reading slot t&1
    __builtin_amdgcn_sched_barrier(0);
    if (t <= 9) stage(t+2, t&1);             // overwrite just-freed slot
    __builtin_amdgcn_sched_barrier(0);
    if (t <= 9) asm volatile("s_waitcnt vmcnt(8)" ::: "memory");   // t+1 landed (own)
    else        asm volatile("s_waitcnt vmcnt(0)" ::: "memory");   // t=10: drain tile 11
    __builtin_amdgcn_sched_barrier(0);
    __builtin_amdgcn_s_barrier();            // everyone's t+1 staging visible
    __builtin_amdgcn_sched_barrier(0);
  }
  compute(AsB + 16384, BsB + 16384);         // tile 11 (slot 1)

  if (sw){
    int c3 = (n0 >= 768);
    u16* dst = c3 ? Kw : Qw;
    float scl = c3 ? 1.0f : 0.180336884f;   // Q: 0.125 * log2(e) folded for exp2 path
    int nb = n0 - c3*768;
    #pragma unroll
    for (int p=0;p<4;p++){
      float4 bv4 = *(const float4*)(bias + n0 + wn + p*16 + quad*4);
      int rem = nb + wn + p*16 + quad*4;
      int hh = rem>>6, d0 = rem&63;
      #pragma unroll
      for (int q=0;q<4;q++){
        int mrow = m0 + wm + q*16 + l15;
        int b = mrow>>10, sl = mrow&1023;
        u16x4 pk;
        pk[0]=f2bf((acc[p][q][0]+bv4.x)*scl); pk[1]=f2bf((acc[p][q][1]+bv4.y)*scl);
        pk[2]=f2bf((acc[p][q][2]+bv4.z)*scl); pk[3]=f2bf((acc[p][q][3]+bv4.w)*scl);
        *(u16x4*)(dst + ((size_t)(b*12+hh)*1024 + sl)*64 + d0) = pk;
      }
    }
  } else {
    #pragma unroll
    for (int q=0;q<4;q++){
      float bv = bias[n0+wn+q*16+l15];
      int rem = (n0-1536) + wn + q*16 + l15;
      int hh = rem>>6, d = rem&63;
      #pragma unroll
      for (int p=0;p<4;p++){
        int mrow = m0 + wm + p*16 + quad*4;
        int b = mrow>>10, sl = mrow&1023;
        u16x4 pk;
        for (int r=0;r<4;r++) pk[r] = f2bf(acc[p][q][r] + bv);
        *(u16x4*)(Vtw + ((size_t)(b*12+hh)*64 + d)*1024 + sl) = pk;
      }
    }
  }
}

// ------ flash attention (round-11 proven + raw v_exp_f32) --------------------------
// grid (96 bh, 8 q-tiles), block 256 = 4 waves; each wave owns 32 queries.
// 32KB LDS (grid gives 3 blocks/CU). Chunk c+1 prefetched global->VGPR during
// compute of c; after the read barrier the relay is ds_written into the same
// buffers. Neither barrier drains global vmcnt. No-max softmax (scores pre-scaled
// by 0.125*log2e): P = exp2(S) via __builtin_amdgcn_exp2f (bare v_exp_f32, no libm
// range fixup -- inputs bounded). Denominators via ones-row MFMA. 96 % 8 == 0 ->
// all q-blocks of a bh share an XCD, K/V reads L2-local.
__global__ void __launch_bounds__(256) attn_k(const u16* __restrict__ Qw,
      const u16* __restrict__ Kw, const u16* __restrict__ Vtw, u16* __restrict__ ctx){
  __shared__ u16 Ks[4096];     // [64 key][64 d]  128B rows, granule ^= key&7
  __shared__ u16 Vts[4096];    // [64 d][64 key]  128B rows, granule ^= d&7
  __shared__ u16 Ps[4][2048];  // per-wave P/O: [32 q][64] 128B rows, granule ^= q&7
  int tid = threadIdx.x, wave = tid>>6, lane = tid&63;
  int l15 = lane&15, quad = lane>>4;
  int bh = blockIdx.x;
  int q0w = blockIdx.y*128 + wave*32;
  const u16* Qb  = Qw + (size_t)bh*65536;
  const char* KbB = (const char*)(Kw + (size_t)bh*65536);
  const char* VbB = (const char*)(Vtw + (size_t)bh*65536);
  char* KsB = (char*)Ks; char* VtsB = (char*)Vts;
  char* PwB = (char*)(&Ps[wave][0]);

  bf16x8 qa[2][2];
  for (int qt=0;qt<2;qt++) for (int c=0;c<2;c++)
    qa[qt][c] = *(const bf16x8*)(Qb + (size_t)(q0w+qt*16+l15)*64 + c*32 + quad*8);

  bf16x8 ones_f;
  for (int t=0;t<8;t++) ones_f[t] = (short)0x3F80;   // bf16 1.0

  f32x4 oacc[4][2] = {};   // [dt][qt]: O^T row d=dt*16+quad*4+r, col q=qt*16+l15
  f32x4 lacc[2] = {};      // denominator (all r equal)

  int rr = tid>>3, gs = tid&7;          // staging: row-in-half / stored granule
  int gsw = (gs ^ (rr&7)) << 4;         // swizzled source granule byte offset
  int ldst = tid*16;
  const char* Kg0 = KbB + (size_t)rr*128      + gsw;   // + c*64*128 per chunk
  const char* Kg1 = KbB + (size_t)(rr+32)*128 + gsw;
  const char* Vg0 = VbB + (size_t)rr*2048      + gsw;  // + c*64*2 per chunk
  const char* Vg1 = VbB + (size_t)(rr+32)*2048 + gsw;

  // stage chunk 0 via relay
  bf16x8 krel0 = *(const bf16x8*)Kg0, krel1 = *(const bf16x8*)Kg1;
  bf16x8 vrel0 = *(const bf16x8*)Vg0, vrel1 = *(const bf16x8*)Vg1;
  *(bf16x8*)(KsB + ldst)  = krel0;  *(bf16x8*)(KsB + 4096 + ldst)  = krel1;
  *(bf16x8*)(VtsB + ldst) = vrel0;  *(bf16x8*)(VtsB + 4096 + ldst) = vrel1;
  __syncthreads();

  for (int c=0; c<16; c++){
    if (c < 15){                          // prefetch chunk c+1 into relay regs
      size_t kk = (size_t)(c+1)*64;
      krel0 = *(const bf16x8*)(Kg0 + kk*128);
      krel1 = *(const bf16x8*)(Kg1 + kk*128);
      vrel0 = *(const bf16x8*)(Vg0 + kk*2);
      vrel1 = *(const bf16x8*)(Vg1 + kk*2);
    }
    // ---- QK: S^T[64k x 32q], K-dim 64 in two 32-chunks ----
    f32x4 st[4][2];
    for (int kt=0;kt<4;kt++){
      int key = kt*16 + l15;
      const char* krow = KsB + key*128;
      bf16x8 ka0 = *(const bf16x8*)(krow + (((quad  ) ^ (key&7))<<4));
      bf16x8 ka1 = *(const bf16x8*)(krow + (((quad+4) ^ (key&7))<<4));
      for (int qt=0;qt<2;qt++){
        f32x4 s = {};
        s = __builtin_amdgcn_mfma_f32_16x16x32_bf16(ka0, qa[qt][0], s, 0,0,0);
        s = __builtin_amdgcn_mfma_f32_16x16x32_bf16(ka1, qa[qt][1], s, 0,0,0);
        st[kt][qt] = s;
      }
    }
    // ---- P = exp2(st) (raw v_exp_f32), pack to bf16, stage to LDS ----
    for (int qt=0;qt<2;qt++){
      int q = qt*16 + l15;
      for (int kt=0;kt<4;kt++){
        u16x4 pk;
        for (int r=0;r<4;r++) pk[r] = f2bf_fast(__builtin_amdgcn_exp2f(st[kt][qt][r]));
        int g = kt*2 + (quad>>1);
        *(u16x4*)(PwB + q*128 + ((g ^ (l15&7))<<4) + (quad&1)*8) = pk;
      }
    }
    // ---- PV: O^T += V^T * P^T ; l += ones * P^T ----
    bf16x8 bp[2][2];
    for (int qt=0;qt<2;qt++){
      int q = qt*16 + l15;
      bp[qt][0] = *(const bf16x8*)(PwB + q*128 + (((quad  ) ^ (l15&7))<<4));
      bp[qt][1] = *(const bf16x8*)(PwB + q*128 + (((quad+4) ^ (l15&7))<<4));
      lacc[qt] = __builtin_amdgcn_mfma_f32_16x16x32_bf16(ones_f, bp[qt][0], lacc[qt], 0,0,0);
      lacc[qt] = __builtin_amdgcn_mfma_f32_16x16x32_bf16(ones_f, bp[qt][1], lacc[qt], 0,0,0);
    }
    for (int dt=0;dt<4;dt++){
      int d = dt*16 + l15;
      const char* vrow = VtsB + d*128;
      bf16x8 av0 = *(const bf16x8*)(vrow + (((quad  ) ^ (d&7))<<4));
      bf16x8 av1 = *(const bf16x8*)(vrow + (((quad+4) ^ (d&7))<<4));
      for (int qt=0;qt<2;qt++){
        oacc[dt][qt] = __builtin_amdgcn_mfma_f32_16x16x32_bf16(av0, bp[qt][0], oacc[dt][qt], 0,0,0);
        oacc[dt][qt] = __builtin_amdgcn_mfma_f32_16x16x32_bf16(av1, bp[qt][1], oacc[dt][qt], 0,0,0);
      }
    }
    __syncthreads();                      // all waves done reading Ks/Vts (lgkm only)
    if (c < 15){
      *(bf16x8*)(KsB + ldst)  = krel0;  *(bf16x8*)(KsB + 4096 + ldst)  = krel1;
      *(bf16x8*)(VtsB + ldst) = vrel0;  *(bf16x8*)(VtsB + 4096 + ldst) = vrel1;
      __syncthreads();                    // staging visible (lgkm only)
    }
  }

  // ---- epilogue: normalize, transpose O^T->O via per-wave Ps, coalesced store ----
  float rinv[2] = { 1.0f/lacc[0][0], 1.0f/lacc[1][0] };
  int b = bh/12, hh = bh - b*12;
  for (int qt=0;qt<2;qt++){
    int q = qt*16 + l15;
    for (int dt=0;dt<4;dt++){
      u16x4 pk;
      for (int r=0;r<4;r++) pk[r] = f2bf_fast(oacc[dt][qt][r]*rinv[qt]);
      int g = dt*2 + (quad>>1);
      *(u16x4*)(PwB + q*128 + ((g ^ (l15&7))<<4) + (quad&1)*8) = pk;
    }
  }
  char* ctxB = (char*)ctx;
  for (int ro=0; ro<4; ro++){            // 32 rows x 8 granules = 4 rounds of 64 lanes
    int q = ro*8 + (lane>>3);
    int gg = lane&7;
    bf16x8 v = *(const bf16x8*)(PwB + q*128 + ((gg ^ (q&7))<<4));
    size_t tok = (size_t)b*1024 + blockIdx.y*128 + wave*32 + q;
    *(bf16x8*)(ctxB + (tok*768 + hh*64 + gg*8)*2) = v;
  }
}

// -------- proj GEMM v3: round-0 geometry + ring-2 global_load_lds pipeline --------
// tile 128m x 64n, grid 768 = 8 xcd x (mg = slot&7, n = slot>>3). 4 waves: each
// 64m x 32n. LDS ring-2: As 2x16KB + Bs 2x8KB = 48KB -> 3 blocks/CU. 6 loads/tile.
__global__ void __launch_bounds__(256) proj_gemm(const u16* __restrict__ A,
      const u16* __restrict__ BT, const float* __restrict__ bias,
      float* __restrict__ of){
  __shared__ u16 As[2*8192];   // 2 x [128 m][64 k]
  __shared__ u16 Bs[2*4096];   // 2 x [64 n][64 k]
  int tid = threadIdx.x, lane = tid&63, wave = tid>>6;
  int l15 = lane&15, quad = lane>>4;
  int bid = blockIdx.x;
  int xcd = bid & 7, slot = bid >> 3;
  int mg = slot & 7, nIdx = slot >> 3;
  int m0 = (xcd*8 + mg)*128, n0 = nIdx*64;
  int wm = (wave>>1)*64, wn = (wave&1)*32;
  f32x4 acc[4][2] = {};
  const char* Ab = (const char*)A; const char* Bb = (const char*)BT;
  char* AsB = (char*)As; char* BsB = (char*)Bs;
  int rsub = lane>>3, g = lane&7;
  const char* Asrc[4]; const char* Bsrc[2];
  #pragma unroll
  for (int h=0;h<4;h++){
    int rl = h*32 + wave*8 + rsub;
    Asrc[h] = Ab + (size_t)(m0+rl)*1536 + ((g ^ (rl&7))<<4);
  }
  #pragma unroll
  for (int h=0;h<2;h++){
    int rl = h*32 + wave*8 + rsub;
    Bsrc[h] = Bb + (size_t)(n0+rl)*1536 + ((g ^ (rl&7))<<4);
  }

  auto stage = [&](int t, int s){
    char* ad = AsB + s*16384 + wave*1024;
    char* bd = BsB + s*8192  + wave*1024;
    size_t ko = (size_t)t*128;
    #pragma unroll
    for (int h=0;h<4;h++) gload16(Asrc[h] + ko, ad + h*4096);
    #pragma unroll
    for (int h=0;h<2;h++) gload16(Bsrc[h] + ko, bd + h*4096);
  };
  auto compute = [&](const char* Abase, const char* Bbase){
    #pragma unroll
    for (int c=0;c<2;c++){
      bf16x8 af[4], bfr[2];
      #pragma unroll
      for (int i=0;i<4;i++){
        int ma = wm + i*16 + l15;
        af[i] = *(const bf16x8*)(Abase + ma*128 + (((c*4+quad) ^ (ma&7))<<4));
      }
      #pragma unroll
      for (int j=0;j<2;j++){
        int nb2 = wn + j*16 + l15;
        bfr[j] = *(const bf16x8*)(Bbase + nb2*128 + (((c*4+quad) ^ (nb2&7))<<4));
      }
      __builtin_amdgcn_s_setprio(1);
      #pragma unroll
      for (int i=0;i<4;i++)
        #pragma unroll
        for (int j=0;j<2;j++)
          acc[i][j] = __builtin_amdgcn_mfma_f32_16x16x32_bf16(af[i], bfr[j], acc[i][j], 0,0,0);
      __builtin_amdgcn_s_setprio(0);
    }
  };

  stage(0, 0);
  stage(1, 1);
  asm volatile("s_waitcnt vmcnt(6)" ::: "memory");
  __builtin_amdgcn_sched_barrier(0);
  __builtin_amdgcn_s_barrier();
  __builtin_amdgcn_sched_barrier(0);

  #pragma unroll 2
  for (int t=0; t<11; t++){
    compute(AsB + (t&1)*16384, BsB + (t&1)*8192);
    __builtin_amdgcn_sched_barrier(0);
    __builtin_amdgcn_s_barrier();            // all waves done reading slot t&1
    __builtin_amdgcn_sched_barrier(0);
    if (t <= 9) stage(t+2, t&1);
    __builtin_amdgcn_sched_barrier(0);
    if (t <= 9) asm volatile("s_waitcnt vmcnt(6)" ::: "memory");
    else        asm volatile("s_waitcnt vmcnt(0)" ::: "memory");
    __builtin_amdgcn_sched_barrier(0);
    __builtin_amdgcn_s_barrier();            // everyone's t+1 staging visible
    __builtin_amdgcn_sched_barrier(0);
  }
  compute(AsB + 16384, BsB + 8192);          // tile 11 (slot 1)

  float bv[2];
  for (int j=0;j<2;j++) bv[j] = bias[n0+wn+j*16+l15];
  #pragma unroll
  for (int i=0;i<4;i++){
    int mb = m0 + wm + i*16 + quad*4;
    #pragma unroll
    for (int j=0;j<2;j++){
      int ncol = wn + j*16 + l15;
      for (int r=0;r<4;r++)
        of[(size_t)(mb+r)*768 + n0 + ncol] = acc[i][j][r] + bv[j];
    }
  }
}

extern "C" void kernel_launch(void* const* d_in, const int* in_sizes, int n_in,
                              void* d_out, int out_size, void* d_ws, size_t ws_size,
                              hipStream_t stream){
  const float* hidden = (const float*)d_in[0];
  const float* wqkv   = (const float*)d_in[1];
  const float* bqkv   = (const float*)d_in[2];
  const float* wproj  = (const float*)d_in[3];
  const float* bproj  = (const float*)d_in[4];
  float* out = (float*)d_out;
  char* ws = (char*)d_ws;
  u16* Acv    = (u16*)(ws);                                   // [8192][768] bf16
  u16* WqkvT  = (u16*)(ws + 12582912);                        // 2304x768
  u16* WprojT = (u16*)(ws + 12582912 + 3538944);              // 768x768
  char* base2 = ws + 12582912 + 3538944 + 1179648;
  u16* Qw     = (u16*)(base2);                                // [96][1024][64] (pre-scaled)
  u16* Kw     = (u16*)(base2 + 12582912);                     // [96][1024][64]
  u16* Vtw    = (u16*)(base2 + (size_t)2*12582912);           // [96][64][1024]
  u16* ctx    = (u16*)(base2 + (size_t)3*12582912);           // [8192][768] bf16

  prep_k<<<5376, 256, 0, stream>>>(hidden, wqkv, wproj, Acv, WqkvT, WprojT);
  qkv_gemm<<<1152, 256, 0, stream>>>(Acv, WqkvT, bqkv, Qw, Kw, Vtw);
  attn_k<<<dim3(96,8), 256, 0, stream>>>(Qw, Kw, Vtw, ctx);
  proj_gemm<<<768, 256, 0, stream>>>(ctx, WprojT, bproj, out);
}